// Round 5
// baseline (211.543 us; speedup 1.0000x reference)
//
#include <hip/hip_runtime.h>
#include <cfloat>

#define BB    128
#define CC    4
#define NBOXN 131072
#define SPLIT 16                 // chunk-blocks per row
#define NBLK  (BB * SPLIT)       // 2048 blocks
#define F4_PER_CHUNK 2048        // 8192 elems / 4
#define F4_PER_STRIPE 8          // float4s per thread

// branchless sorted-insert into descending triple (a>=b>=c)
__device__ __forceinline__ void ins3(float v, float& a, float& b, float& c) {
    float m1 = fminf(a, v); a = fmaxf(a, v);
    float m2 = fminf(b, m1); b = fmaxf(b, m1);
    c = fmaxf(c, m2);
}

__device__ __forceinline__ float bce(float x, float t) {
    return fmaxf(x, 0.0f) - x * t + log1pf(expf(-fabsf(x)));
}

// Fused: per-chunk exact top-3 (anchor excluded) + last-block finalize.
__global__ __launch_bounds__(256) void k_fused(
        const float* __restrict__ cp,
        const float* __restrict__ rp,
        const int*   __restrict__ box_idxs,
        const float* __restrict__ rt,
        float*       __restrict__ cand,     // [NBLK*3]
        float*       __restrict__ posval,   // [BB]
        float*       __restrict__ rowreg,   // [BB*CC]
        unsigned*    __restrict__ counter,  // [1], zeroed per launch
        float*       __restrict__ out) {
    const int row   = blockIdx.x >> 4;
    const int chunk = blockIdx.x & 15;
    const int tid   = threadIdx.x;
    const int bidx  = box_idxs[row];

    // side jobs hidden under the stream: reg gathers + positive logit
    if (chunk == 0) {
        if (tid < CC) {
            const float pv = rp[((size_t)row * CC + tid) * NBOXN + bidx];
            const float d  = fabsf(pv - rt[row * CC + tid]);
            rowreg[row * CC + tid] = (d < 1.0f) ? 0.5f * d * d : (d - 0.5f);
        } else if (tid == CC) {
            posval[row] = cp[(size_t)row * NBOXN + bidx];
        }
    }

    const float4* src = reinterpret_cast<const float4*>(cp + (size_t)row * NBOXN)
                        + chunk * F4_PER_CHUNK;
    const int gbase = (chunk * F4_PER_CHUNK) << 2;

    // branchless per-thread exact top-3 of this thread's 32 elements
    float a = -FLT_MAX, b = -FLT_MAX, c = -FLT_MAX;
    #pragma unroll
    for (int k = 0; k < F4_PER_STRIPE; ++k) {
        const int j = tid + (k << 8);
        float4 v = src[j];
        const int g = gbase + (j << 2);
        if ((unsigned)(bidx - g) < 4u) {     // rare, exec-mask-skipped
            if      (bidx == g)     v.x = -FLT_MAX;
            else if (bidx == g + 1) v.y = -FLT_MAX;
            else if (bidx == g + 2) v.z = -FLT_MAX;
            else                    v.w = -FLT_MAX;
        }
        ins3(v.x, a, b, c); ins3(v.y, a, b, c);
        ins3(v.z, a, b, c); ins3(v.w, a, b, c);
    }

    // wave64 shuffle tree; lane 0's cone covers all 64 lanes exactly once
    for (int off = 32; off >= 1; off >>= 1) {
        const float a2 = __shfl_down(a, off);
        const float b2 = __shfl_down(b, off);
        const float c2 = __shfl_down(c, off);
        ins3(a2, a, b, c); ins3(b2, a, b, c); ins3(c2, a, b, c);
    }

    __shared__ float sv[4][3];
    const int lane = tid & 63, wave = tid >> 6;
    if (lane == 0) { sv[wave][0] = a; sv[wave][1] = b; sv[wave][2] = c; }
    __syncthreads();
    if (tid == 0) {
        for (int w = 1; w < 4; ++w) {
            ins3(sv[w][0], a, b, c);
            ins3(sv[w][1], a, b, c);
            ins3(sv[w][2], a, b, c);
        }
        float* dst = cand + (size_t)blockIdx.x * 3;
        dst[0] = a; dst[1] = b; dst[2] = c;
    }

    // ---- last-block-done handoff ----
    __shared__ bool amLast;
    __threadfence();                         // release: cand/posval/rowreg
    __syncthreads();
    if (tid == 0) {
        const unsigned old = atomicAdd(counter, 1u);
        amLast = (old == NBLK - 1);
    }
    __syncthreads();
    if (!amLast) return;
    __threadfence();                         // acquire

    // ---- finalize (one block, 128 working threads: one row each) ----
    __shared__ float sm2[2];
    if (tid < BB) {
        const int r = tid;
        float ra = -FLT_MAX, rb = -FLT_MAX, rc = -FLT_MAX;
        const float* p = cand + (size_t)r * SPLIT * 3;
        #pragma unroll
        for (int k = 0; k < SPLIT * 3; ++k) ins3(p[k], ra, rb, rc);

        float loss = bce(posval[r], 1.0f)
                   + bce(ra, 0.0f) + bce(rb, 0.0f) + bce(rc, 0.0f);
        loss += rowreg[r * CC + 0] + rowreg[r * CC + 1]
              + rowreg[r * CC + 2] + rowreg[r * CC + 3];

        for (int off = 32; off >= 1; off >>= 1) loss += __shfl_down(loss, off);
        if ((tid & 63) == 0) sm2[tid >> 6] = loss;
    }
    __syncthreads();
    if (tid == 0) out[0] = (sm2[0] + sm2[1]) * (1.0f / (BB * CC));
}

extern "C" void kernel_launch(void* const* d_in, const int* in_sizes, int n_in,
                              void* d_out, int out_size, void* d_ws, size_t ws_size,
                              hipStream_t stream) {
    const float* class_preds = (const float*)d_in[0];
    const float* reg_preds   = (const float*)d_in[1];
    const int*   box_idxs    = (const int*)d_in[2];
    const float* reg_targs   = (const float*)d_in[3];
    float* out = (float*)d_out;

    float*    cand    = (float*)d_ws;                       // NBLK*3 floats
    float*    posval  = cand + (size_t)NBLK * 3;            // BB floats
    float*    rowreg  = posval + BB;                        // BB*CC floats
    unsigned* counter = (unsigned*)(rowreg + BB * CC);      // 1 uint

    hipMemsetAsync(counter, 0, sizeof(unsigned), stream);   // capturable fill node
    k_fused<<<NBLK, 256, 0, stream>>>(class_preds, reg_preds, box_idxs,
                                      reg_targs, cand, posval, rowreg,
                                      counter, out);
}

// Round 6
// 44.503 us; speedup vs baseline: 4.7534x; 4.7534x over previous
//
#include <hip/hip_runtime.h>
#include <cfloat>

#define BB    128
#define CC    4
#define NBOXN 131072
#define SPLIT 16                 // chunk-blocks per row
#define NBLK  (BB * SPLIT)       // 2048 blocks
#define F4_PER_CHUNK 2048        // 8192 elems / 4
#define F4_PER_STRIPE 8          // float4s per thread

// branchless sorted-insert into descending triple (a>=b>=c)
__device__ __forceinline__ void ins3(float v, float& a, float& b, float& c) {
    float m1 = fminf(a, v); a = fmaxf(a, v);
    float m2 = fminf(b, m1); b = fmaxf(b, m1);
    c = fmaxf(c, m2);
}

__device__ __forceinline__ float bce(float x, float t) {
    return fmaxf(x, 0.0f) - x * t + log1pf(expf(-fabsf(x)));
}

// agent-scope (device) coherent store/load: single instruction with sc0/sc1,
// no cache-flush fences. Lines touched this way are never cached in L1/L2.
__device__ __forceinline__ void st_agent(float* p, float v) {
    __hip_atomic_store(p, v, __ATOMIC_RELAXED, __HIP_MEMORY_SCOPE_AGENT);
}
__device__ __forceinline__ float ld_agent(const float* p) {
    return __hip_atomic_load(p, __ATOMIC_RELAXED, __HIP_MEMORY_SCOPE_AGENT);
}

// Fused: per-chunk exact top-3 (anchor excluded) + last-block finalize,
// fence-free via scoped atomics.
__global__ __launch_bounds__(256) void k_fused(
        const float* __restrict__ cp,
        const float* __restrict__ rp,
        const int*   __restrict__ box_idxs,
        const float* __restrict__ rt,
        float*       __restrict__ cand,     // [NBLK*3]
        float*       __restrict__ posval,   // [BB]
        float*       __restrict__ rowreg,   // [BB*CC]
        unsigned*    __restrict__ counter,  // [1], zeroed per launch
        float*       __restrict__ out) {
    const int row   = blockIdx.x >> 4;
    const int chunk = blockIdx.x & 15;
    const int tid   = threadIdx.x;
    const int bidx  = box_idxs[row];

    // side jobs hidden under the stream: reg gathers + positive logit
    if (chunk == 0) {
        if (tid < CC) {
            const float pv = rp[((size_t)row * CC + tid) * NBOXN + bidx];
            const float d  = fabsf(pv - rt[row * CC + tid]);
            st_agent(&rowreg[row * CC + tid], (d < 1.0f) ? 0.5f * d * d : (d - 0.5f));
        } else if (tid == CC) {
            st_agent(&posval[row], cp[(size_t)row * NBOXN + bidx]);
        }
    }

    const float4* src = reinterpret_cast<const float4*>(cp + (size_t)row * NBOXN)
                        + chunk * F4_PER_CHUNK;
    const int gbase = (chunk * F4_PER_CHUNK) << 2;

    // branchless per-thread exact top-3 of this thread's 32 elements
    float a = -FLT_MAX, b = -FLT_MAX, c = -FLT_MAX;
    #pragma unroll
    for (int k = 0; k < F4_PER_STRIPE; ++k) {
        const int j = tid + (k << 8);
        float4 v = src[j];
        const int g = gbase + (j << 2);
        if ((unsigned)(bidx - g) < 4u) {     // rare, exec-mask-skipped
            if      (bidx == g)     v.x = -FLT_MAX;
            else if (bidx == g + 1) v.y = -FLT_MAX;
            else if (bidx == g + 2) v.z = -FLT_MAX;
            else                    v.w = -FLT_MAX;
        }
        ins3(v.x, a, b, c); ins3(v.y, a, b, c);
        ins3(v.z, a, b, c); ins3(v.w, a, b, c);
    }

    // wave64 shuffle tree; lane 0's cone covers all 64 lanes exactly once
    for (int off = 32; off >= 1; off >>= 1) {
        const float a2 = __shfl_down(a, off);
        const float b2 = __shfl_down(b, off);
        const float c2 = __shfl_down(c, off);
        ins3(a2, a, b, c); ins3(b2, a, b, c); ins3(c2, a, b, c);
    }

    __shared__ float sv[4][3];
    const int lane = tid & 63, wave = tid >> 6;
    if (lane == 0) { sv[wave][0] = a; sv[wave][1] = b; sv[wave][2] = c; }
    __syncthreads();
    if (tid == 0) {
        for (int w = 1; w < 4; ++w) {
            ins3(sv[w][0], a, b, c);
            ins3(sv[w][1], a, b, c);
            ins3(sv[w][2], a, b, c);
        }
        float* dst = cand + (size_t)blockIdx.x * 3;
        st_agent(&dst[0], a); st_agent(&dst[1], b); st_agent(&dst[2], c);
    }

    // ---- last-block-done handoff (fence-free) ----
    // __syncthreads drains vmcnt(0) for every wave, so all of this block's
    // sc1 stores are complete at the coherence point (L3) before tid0's
    // relaxed agent-scope atomicAdd can be observed by anyone.
    __shared__ bool amLast;
    __syncthreads();
    if (tid == 0) {
        const unsigned old = __hip_atomic_fetch_add(
            counter, 1u, __ATOMIC_RELAXED, __HIP_MEMORY_SCOPE_AGENT);
        amLast = (old == NBLK - 1);
    }
    __syncthreads();
    if (!amLast) return;

    // ---- finalize (one block, 128 working threads: one row each) ----
    // All reads via agent-scope loads (L1/L2 never hold these lines).
    __shared__ float sm2[2];
    if (tid < BB) {
        const int r = tid;
        float ra = -FLT_MAX, rb = -FLT_MAX, rc = -FLT_MAX;
        const float* p = cand + (size_t)r * SPLIT * 3;
        #pragma unroll
        for (int k = 0; k < SPLIT * 3; ++k) ins3(ld_agent(&p[k]), ra, rb, rc);

        float loss = bce(ld_agent(&posval[r]), 1.0f)
                   + bce(ra, 0.0f) + bce(rb, 0.0f) + bce(rc, 0.0f);
        loss += ld_agent(&rowreg[r * CC + 0]) + ld_agent(&rowreg[r * CC + 1])
              + ld_agent(&rowreg[r * CC + 2]) + ld_agent(&rowreg[r * CC + 3]);

        for (int off = 32; off >= 1; off >>= 1) loss += __shfl_down(loss, off);
        if ((tid & 63) == 0) sm2[tid >> 6] = loss;
    }
    __syncthreads();
    if (tid == 0) out[0] = (sm2[0] + sm2[1]) * (1.0f / (BB * CC));
}

extern "C" void kernel_launch(void* const* d_in, const int* in_sizes, int n_in,
                              void* d_out, int out_size, void* d_ws, size_t ws_size,
                              hipStream_t stream) {
    const float* class_preds = (const float*)d_in[0];
    const float* reg_preds   = (const float*)d_in[1];
    const int*   box_idxs    = (const int*)d_in[2];
    const float* reg_targs   = (const float*)d_in[3];
    float* out = (float*)d_out;

    float*    cand    = (float*)d_ws;                       // NBLK*3 floats
    float*    posval  = cand + (size_t)NBLK * 3;            // BB floats
    float*    rowreg  = posval + BB;                        // BB*CC floats
    unsigned* counter = (unsigned*)(rowreg + BB * CC);      // 1 uint

    hipMemsetAsync(counter, 0, sizeof(unsigned), stream);   // capturable fill node
    k_fused<<<NBLK, 256, 0, stream>>>(class_preds, reg_preds, box_idxs,
                                      reg_targs, cand, posval, rowreg,
                                      counter, out);
}

// Round 7
// 39.879 us; speedup vs baseline: 5.3047x; 1.1160x over previous
//
#include <hip/hip_runtime.h>
#include <cfloat>

#define BB    128
#define CC    4
#define NBOXN 131072
#define SPLIT 16                 // chunk-blocks per row
#define NBLK  (BB * SPLIT)       // 2048 blocks
#define F4_PER_CHUNK 2048        // 8192 elems / 4
#define F4_PER_STRIPE 8          // float4s per thread

typedef float v4f __attribute__((ext_vector_type(4)));

// branchless sorted-insert into descending triple (a>=b>=c)
__device__ __forceinline__ void ins3(float v, float& a, float& b, float& c) {
    float m1 = fminf(a, v); a = fmaxf(a, v);
    float m2 = fminf(b, m1); b = fmaxf(b, m1);
    c = fmaxf(c, m2);
}

__device__ __forceinline__ float bce(float x, float t) {
    return fmaxf(x, 0.0f) - x * t + log1pf(expf(-fabsf(x)));
}

// agent-scope (device) coherent store: single global_store with sc0/sc1,
// bypasses L1/L2 -> value lands at the coherence point (L3). Fire-and-forget.
__device__ __forceinline__ void st_agent(float* p, float v) {
    __hip_atomic_store(p, v, __ATOMIC_RELAXED, __HIP_MEMORY_SCOPE_AGENT);
}

// Fused: per-chunk exact top-3 (anchor excluded) + last-block finalize.
// Cross-block writes use sc1 stores; the finalize reads with PLAIN loads —
// legal because these lines are never dirtied in any L1/L2 this dispatch
// (sc1 stores bypass them, and dispatch-start acquire invalidated leftovers).
__global__ __launch_bounds__(256) void k_fused(
        const float* __restrict__ cp,
        const float* __restrict__ rp,
        const int*   __restrict__ box_idxs,
        const float* __restrict__ rt,
        float*       __restrict__ cand,     // [NBLK*3]
        float*       __restrict__ posval,   // [BB]
        float*       __restrict__ rowreg,   // [BB*CC]
        unsigned*    __restrict__ counter,  // [1], zeroed per launch
        float*       __restrict__ out) {
    const int row   = blockIdx.x >> 4;
    const int chunk = blockIdx.x & 15;
    const int tid   = threadIdx.x;
    const int bidx  = box_idxs[row];

    // side jobs hidden under the stream: reg gathers + positive logit
    if (chunk == 0) {
        if (tid < CC) {
            const float pv = rp[((size_t)row * CC + tid) * NBOXN + bidx];
            const float d  = fabsf(pv - rt[row * CC + tid]);
            st_agent(&rowreg[row * CC + tid], (d < 1.0f) ? 0.5f * d * d : (d - 0.5f));
        } else if (tid == CC) {
            st_agent(&posval[row], cp[(size_t)row * NBOXN + bidx]);
        }
    }

    const v4f* src = reinterpret_cast<const v4f*>(cp + (size_t)row * NBOXN)
                     + chunk * F4_PER_CHUNK;
    const int gbase = (chunk * F4_PER_CHUNK) << 2;

    // branchless per-thread exact top-3 of this thread's 32 elements,
    // nontemporal loads (read-once stream, keep out of L2)
    float a = -FLT_MAX, b = -FLT_MAX, c = -FLT_MAX;
    #pragma unroll
    for (int k = 0; k < F4_PER_STRIPE; ++k) {
        const int j = tid + (k << 8);
        v4f v = __builtin_nontemporal_load(&src[j]);
        const int g = gbase + (j << 2);
        if ((unsigned)(bidx - g) < 4u) {     // rare, exec-mask-skipped
            if      (bidx == g)     v.x = -FLT_MAX;
            else if (bidx == g + 1) v.y = -FLT_MAX;
            else if (bidx == g + 2) v.z = -FLT_MAX;
            else                    v.w = -FLT_MAX;
        }
        ins3(v.x, a, b, c); ins3(v.y, a, b, c);
        ins3(v.z, a, b, c); ins3(v.w, a, b, c);
    }

    // wave64 shuffle tree; lane 0's cone covers all 64 lanes exactly once
    for (int off = 32; off >= 1; off >>= 1) {
        const float a2 = __shfl_down(a, off);
        const float b2 = __shfl_down(b, off);
        const float c2 = __shfl_down(c, off);
        ins3(a2, a, b, c); ins3(b2, a, b, c); ins3(c2, a, b, c);
    }

    __shared__ float sv[4][3];
    const int lane = tid & 63, wave = tid >> 6;
    if (lane == 0) { sv[wave][0] = a; sv[wave][1] = b; sv[wave][2] = c; }
    __syncthreads();
    if (tid == 0) {
        for (int w = 1; w < 4; ++w) {
            ins3(sv[w][0], a, b, c);
            ins3(sv[w][1], a, b, c);
            ins3(sv[w][2], a, b, c);
        }
        float* dst = cand + (size_t)blockIdx.x * 3;
        st_agent(&dst[0], a); st_agent(&dst[1], b); st_agent(&dst[2], c);
    }

    // ---- last-block-done handoff ----
    // __syncthreads drains vmcnt for every wave, so all this block's sc1
    // stores reached L3 before tid0's agent-scope atomicAdd is visible.
    __shared__ bool amLast;
    __syncthreads();
    if (tid == 0) {
        const unsigned old = __hip_atomic_fetch_add(
            counter, 1u, __ATOMIC_RELAXED, __HIP_MEMORY_SCOPE_AGENT);
        amLast = (old == NBLK - 1);
    }
    __syncthreads();
    if (!amLast) return;

    // ---- finalize (one block, 128 working threads: one row each) ----
    // PLAIN loads: compiler batches them (this was R6's 24 us mistake).
    __shared__ float sm2[2];
    if (tid < BB) {
        const int r = tid;
        float ra = -FLT_MAX, rb = -FLT_MAX, rc = -FLT_MAX;
        const float* p = cand + (size_t)r * SPLIT * 3;
        #pragma unroll
        for (int k = 0; k < SPLIT * 3; ++k) ins3(p[k], ra, rb, rc);

        float loss = bce(posval[r], 1.0f)
                   + bce(ra, 0.0f) + bce(rb, 0.0f) + bce(rc, 0.0f);
        loss += rowreg[r * CC + 0] + rowreg[r * CC + 1]
              + rowreg[r * CC + 2] + rowreg[r * CC + 3];

        for (int off = 32; off >= 1; off >>= 1) loss += __shfl_down(loss, off);
        if ((tid & 63) == 0) sm2[tid >> 6] = loss;
    }
    __syncthreads();
    if (tid == 0) out[0] = (sm2[0] + sm2[1]) * (1.0f / (BB * CC));
}

extern "C" void kernel_launch(void* const* d_in, const int* in_sizes, int n_in,
                              void* d_out, int out_size, void* d_ws, size_t ws_size,
                              hipStream_t stream) {
    const float* class_preds = (const float*)d_in[0];
    const float* reg_preds   = (const float*)d_in[1];
    const int*   box_idxs    = (const int*)d_in[2];
    const float* reg_targs   = (const float*)d_in[3];
    float* out = (float*)d_out;

    float*    cand    = (float*)d_ws;                       // NBLK*3 floats
    float*    posval  = cand + (size_t)NBLK * 3;            // BB floats
    float*    rowreg  = posval + BB;                        // BB*CC floats
    unsigned* counter = (unsigned*)(rowreg + BB * CC);      // 1 uint

    hipMemsetAsync(counter, 0, sizeof(unsigned), stream);   // capturable fill node
    k_fused<<<NBLK, 256, 0, stream>>>(class_preds, reg_preds, box_idxs,
                                      reg_targs, cand, posval, rowreg,
                                      counter, out);
}

// Round 8
// 22.607 us; speedup vs baseline: 9.3573x; 1.7640x over previous
//
#include <hip/hip_runtime.h>
#include <cfloat>

#define BB    128
#define CC    4
#define NBOXN 131072
#define K1CHUNKS 15              // K1 covers chunks 0..14; K2 covers chunk 15
#define F4_PER_CHUNK 2048        // 8192 elems / 4
#define F4_PER_STRIPE 8          // float4s per thread (256 threads/chunk)
#define CAND_STRIDE 48           // floats per row in cand (15 used, pad to 48)

typedef float v4f __attribute__((ext_vector_type(4)));

// branchless sorted-insert into descending triple (a>=b>=c)
__device__ __forceinline__ void ins3(float v, float& a, float& b, float& c) {
    float m1 = fminf(a, v); a = fmaxf(a, v);
    float m2 = fminf(b, m1); b = fmaxf(b, m1);
    c = fmaxf(c, m2);
}

__device__ __forceinline__ float bce(float x, float t) {
    return fmaxf(x, 0.0f) - x * t + log1pf(expf(-fabsf(x)));
}

// per-thread triple of 8 float4s starting at src (stride 256 f4), excluding
// the anchor if it falls in this thread's stripe. chunk_f4 = first f4 index
// of this chunk within the row.
__device__ __forceinline__ void stripe_top3(
        const v4f* __restrict__ src, int tid, int chunk_f4, int bidx,
        float& a, float& b, float& c) {
    a = -FLT_MAX; b = -FLT_MAX; c = -FLT_MAX;
    #pragma unroll
    for (int k = 0; k < F4_PER_STRIPE; ++k) {
        const v4f v = src[tid + (k << 8)];
        ins3(v.x, a, b, c); ins3(v.y, a, b, c);
        ins3(v.z, a, b, c); ins3(v.w, a, b, c);
    }
    // anchor fixup: at most ONE thread in the entire grid re-does its stripe
    const int lq = (bidx >> 2) - chunk_f4;   // local f4 index of anchor
    if (lq >= 0 && lq < F4_PER_CHUNK && (lq & 255) == tid) {
        a = -FLT_MAX; b = -FLT_MAX; c = -FLT_MAX;
        #pragma unroll
        for (int k = 0; k < F4_PER_STRIPE; ++k) {
            const int j = tid + (k << 8);
            v4f v = src[j];                  // L1-hot re-read
            const int g = (chunk_f4 + j) << 2;
            if      (bidx == g)     v.x = -FLT_MAX;
            else if (bidx == g + 1) v.y = -FLT_MAX;
            else if (bidx == g + 2) v.z = -FLT_MAX;
            else if (bidx == g + 3) v.w = -FLT_MAX;
            ins3(v.x, a, b, c); ins3(v.y, a, b, c);
            ins3(v.z, a, b, c); ins3(v.w, a, b, c);
        }
    }
}

// wave shuffle tree + 4-wave LDS merge; returns exact block triple in tid 0.
__device__ __forceinline__ void block_top3(
        int tid, float& a, float& b, float& c, float (*sv)[3]) {
    for (int off = 32; off >= 1; off >>= 1) {
        const float a2 = __shfl_down(a, off);
        const float b2 = __shfl_down(b, off);
        const float c2 = __shfl_down(c, off);
        ins3(a2, a, b, c); ins3(b2, a, b, c); ins3(c2, a, b, c);
    }
    const int lane = tid & 63, wave = tid >> 6;
    if (lane == 0) { sv[wave][0] = a; sv[wave][1] = b; sv[wave][2] = c; }
    __syncthreads();
    if (tid == 0) {
        for (int w = 1; w < 4; ++w) {
            ins3(sv[w][0], a, b, c);
            ins3(sv[w][1], a, b, c);
            ins3(sv[w][2], a, b, c);
        }
    }
}

// ---- Kernel 1: chunks 0..14 of every row -> exact per-chunk top-3 ----
__global__ __launch_bounds__(256) void k_chunks(
        const float* __restrict__ cp,
        const int*   __restrict__ box_idxs,
        float*       __restrict__ cand,     // [BB*CAND_STRIDE]
        float*       __restrict__ out) {
    const int row   = blockIdx.x / K1CHUNKS;
    const int chunk = blockIdx.x % K1CHUNKS;
    const int tid   = threadIdx.x;
    if (blockIdx.x == 0 && tid == 0) out[0] = 0.0f;  // visible to K2 at boundary

    const int bidx = box_idxs[row];
    const v4f* src = reinterpret_cast<const v4f*>(cp + (size_t)row * NBOXN)
                     + chunk * F4_PER_CHUNK;

    float a, b, c;
    stripe_top3(src, tid, chunk * F4_PER_CHUNK, bidx, a, b, c);

    __shared__ float sv[4][3];
    block_top3(tid, a, b, c, sv);
    if (tid == 0) {
        float* dst = cand + (size_t)row * CAND_STRIDE + chunk * 3;
        dst[0] = a; dst[1] = b; dst[2] = c;
    }
}

// ---- Kernel 2: chunk 15 stream + row merge + loss + atomic accumulate ----
__global__ __launch_bounds__(256) void k_final(
        const float* __restrict__ cp,
        const float* __restrict__ rp,
        const int*   __restrict__ box_idxs,
        const float* __restrict__ rt,
        const float* __restrict__ cand,
        float*       __restrict__ out) {
    const int row = blockIdx.x;
    const int tid = threadIdx.x;
    const int bidx = box_idxs[row];

    // early scalar gathers (one thread), latency hidden under the stream
    float pos = 0.0f, pv0 = 0, pv1 = 0, pv2 = 0, pv3 = 0, t0 = 0, t1 = 0, t2 = 0, t3 = 0;
    if (tid == 0) {
        pos = cp[(size_t)row * NBOXN + bidx];
        pv0 = rp[((size_t)row * CC + 0) * NBOXN + bidx];
        pv1 = rp[((size_t)row * CC + 1) * NBOXN + bidx];
        pv2 = rp[((size_t)row * CC + 2) * NBOXN + bidx];
        pv3 = rp[((size_t)row * CC + 3) * NBOXN + bidx];
        t0 = rt[row * CC + 0]; t1 = rt[row * CC + 1];
        t2 = rt[row * CC + 2]; t3 = rt[row * CC + 3];
    }

    const int chunk_f4 = K1CHUNKS * F4_PER_CHUNK;   // chunk 15 start (f4 units)
    const v4f* src = reinterpret_cast<const v4f*>(cp + (size_t)row * NBOXN)
                     + chunk_f4;

    float a, b, c;
    stripe_top3(src, tid, chunk_f4, bidx, a, b, c);

    // inject the row's 15 K1 candidates into wave-0 lanes 0..44
    if (tid < K1CHUNKS * 3)
        ins3(cand[(size_t)row * CAND_STRIDE + tid], a, b, c);

    __shared__ float sv[4][3];
    block_top3(tid, a, b, c, sv);

    if (tid == 0) {
        float loss = bce(pos, 1.0f) + bce(a, 0.0f) + bce(b, 0.0f) + bce(c, 0.0f);
        float d;
        d = fabsf(pv0 - t0); loss += (d < 1.0f) ? 0.5f * d * d : (d - 0.5f);
        d = fabsf(pv1 - t1); loss += (d < 1.0f) ? 0.5f * d * d : (d - 0.5f);
        d = fabsf(pv2 - t2); loss += (d < 1.0f) ? 0.5f * d * d : (d - 0.5f);
        d = fabsf(pv3 - t3); loss += (d < 1.0f) ? 0.5f * d * d : (d - 0.5f);
        atomicAdd(out, loss * (1.0f / (BB * CC)));  // device-scope by default
    }
}

extern "C" void kernel_launch(void* const* d_in, const int* in_sizes, int n_in,
                              void* d_out, int out_size, void* d_ws, size_t ws_size,
                              hipStream_t stream) {
    const float* class_preds = (const float*)d_in[0];
    const float* reg_preds   = (const float*)d_in[1];
    const int*   box_idxs    = (const int*)d_in[2];
    const float* reg_targs   = (const float*)d_in[3];
    float* out  = (float*)d_out;
    float* cand = (float*)d_ws;   // BB*CAND_STRIDE floats = 24 KB

    k_chunks<<<BB * K1CHUNKS, 256, 0, stream>>>(class_preds, box_idxs, cand, out);
    k_final <<<BB,            256, 0, stream>>>(class_preds, reg_preds, box_idxs,
                                                reg_targs, cand, out);
}

// Round 9
// 17.080 us; speedup vs baseline: 12.3851x; 1.3236x over previous
//
#include <hip/hip_runtime.h>
#include <cfloat>

#define BB    128
#define CC    4
#define NBOXN 131072
#define SPLIT 16                 // chunk-blocks per row
#define NBLK  (BB * SPLIT)       // 2048 blocks = 8/CU exactly
#define F4_PER_CHUNK 2048        // 8192 elems / 4
#define F4_PER_STRIPE 8          // float4s per thread

typedef float v4f __attribute__((ext_vector_type(4)));

// branchless sorted-insert into descending triple (a>=b>=c)
__device__ __forceinline__ void ins3(float v, float& a, float& b, float& c) {
    float m1 = fminf(a, v); a = fmaxf(a, v);
    float m2 = fminf(b, m1); b = fmaxf(b, m1);
    c = fmaxf(c, m2);
}

__device__ __forceinline__ float bce(float x, float t) {
    return fmaxf(x, 0.0f) - x * t + log1pf(expf(-fabsf(x)));
}

// ---- Kernel 1: exact per-chunk top-3 (anchor excluded), NT stream ----
__global__ __launch_bounds__(256) void k_chunk_top3(
        const float* __restrict__ cp,
        const float* __restrict__ rp,
        const int*   __restrict__ box_idxs,
        const float* __restrict__ rt,
        float*       __restrict__ cand,     // [NBLK*3]
        float*       __restrict__ posval,   // [BB]
        float*       __restrict__ rowreg) { // [BB*CC]
    const int row   = blockIdx.x >> 4;
    const int chunk = blockIdx.x & 15;
    const int tid   = threadIdx.x;
    const int bidx  = box_idxs[row];

    // side jobs hidden under the stream (one chunk-0 block per row)
    if (chunk == 0) {
        if (tid < CC) {
            const float pv = rp[((size_t)row * CC + tid) * NBOXN + bidx];
            const float d  = fabsf(pv - rt[row * CC + tid]);
            rowreg[row * CC + tid] = (d < 1.0f) ? 0.5f * d * d : (d - 0.5f);
        } else if (tid == CC) {
            posval[row] = cp[(size_t)row * NBOXN + bidx];
        }
    }

    const v4f* src = reinterpret_cast<const v4f*>(cp + (size_t)row * NBOXN)
                     + chunk * F4_PER_CHUNK;
    const int gbase = (chunk * F4_PER_CHUNK) << 2;

    // branchless per-thread exact top-3; nontemporal read-once stream
    float a = -FLT_MAX, b = -FLT_MAX, c = -FLT_MAX;
    #pragma unroll
    for (int k = 0; k < F4_PER_STRIPE; ++k) {
        const int j = tid + (k << 8);
        v4f v = __builtin_nontemporal_load(&src[j]);
        const int g = gbase + (j << 2);
        if ((unsigned)(bidx - g) < 4u) {     // rare, exec-mask-skipped
            if      (bidx == g)     v.x = -FLT_MAX;
            else if (bidx == g + 1) v.y = -FLT_MAX;
            else if (bidx == g + 2) v.z = -FLT_MAX;
            else                    v.w = -FLT_MAX;
        }
        ins3(v.x, a, b, c); ins3(v.y, a, b, c);
        ins3(v.z, a, b, c); ins3(v.w, a, b, c);
    }

    // wave64 shuffle tree; lane 0's cone covers all 64 lanes exactly once
    for (int off = 32; off >= 1; off >>= 1) {
        const float a2 = __shfl_down(a, off);
        const float b2 = __shfl_down(b, off);
        const float c2 = __shfl_down(c, off);
        ins3(a2, a, b, c); ins3(b2, a, b, c); ins3(c2, a, b, c);
    }

    __shared__ float sv[4][3];
    const int lane = tid & 63, wave = tid >> 6;
    if (lane == 0) { sv[wave][0] = a; sv[wave][1] = b; sv[wave][2] = c; }
    __syncthreads();
    if (tid == 0) {
        for (int w = 1; w < 4; ++w) {
            ins3(sv[w][0], a, b, c);
            ins3(sv[w][1], a, b, c);
            ins3(sv[w][2], a, b, c);
        }
        float* dst = cand + (size_t)blockIdx.x * 3;
        dst[0] = a; dst[1] = b; dst[2] = c;
    }
}

// ---- Kernel 2: merge 48 exact candidates/row + loss + scalar reduce ----
__global__ __launch_bounds__(128) void k_final(
        const float* __restrict__ cand,
        const float* __restrict__ posval,
        const float* __restrict__ rowreg,
        float*       __restrict__ out) {
    const int r = threadIdx.x;   // one row per thread

    // issue all independent loads up front: 12 x dwordx4 (cand row, 192 B
    // aligned) + 1 x dwordx4 (rowreg) + scalar posval — batched by compiler
    const v4f* pc = reinterpret_cast<const v4f*>(cand + (size_t)r * SPLIT * 3);
    v4f cv[12];
    #pragma unroll
    for (int q = 0; q < 12; ++q) cv[q] = pc[q];
    const v4f rg = reinterpret_cast<const v4f*>(rowreg)[r];
    const float pos = posval[r];

    float a = -FLT_MAX, b = -FLT_MAX, c = -FLT_MAX;
    #pragma unroll
    for (int q = 0; q < 12; ++q) {
        ins3(cv[q].x, a, b, c); ins3(cv[q].y, a, b, c);
        ins3(cv[q].z, a, b, c); ins3(cv[q].w, a, b, c);
    }

    float loss = bce(pos, 1.0f) + bce(a, 0.0f) + bce(b, 0.0f) + bce(c, 0.0f);
    loss += rg.x + rg.y + rg.z + rg.w;

    for (int off = 32; off >= 1; off >>= 1) loss += __shfl_down(loss, off);
    __shared__ float sm[2];
    if ((r & 63) == 0) sm[r >> 6] = loss;
    __syncthreads();
    if (r == 0) out[0] = (sm[0] + sm[1]) * (1.0f / (BB * CC));
}

extern "C" void kernel_launch(void* const* d_in, const int* in_sizes, int n_in,
                              void* d_out, int out_size, void* d_ws, size_t ws_size,
                              hipStream_t stream) {
    const float* class_preds = (const float*)d_in[0];
    const float* reg_preds   = (const float*)d_in[1];
    const int*   box_idxs    = (const int*)d_in[2];
    const float* reg_targs   = (const float*)d_in[3];
    float* out = (float*)d_out;

    float* cand   = (float*)d_ws;                   // NBLK*3 floats
    float* posval = cand + (size_t)NBLK * 3;        // BB floats
    float* rowreg = posval + BB;                    // BB*CC floats

    k_chunk_top3<<<NBLK, 256, 0, stream>>>(class_preds, reg_preds,
                                           box_idxs, reg_targs,
                                           cand, posval, rowreg);
    k_final<<<1, 128, 0, stream>>>(cand, posval, rowreg, out);
}

// Round 10
// 16.506 us; speedup vs baseline: 12.8159x; 1.0348x over previous
//
#include <hip/hip_runtime.h>
#include <cfloat>

#define BB    128
#define CC    4
#define NBOXN 131072
#define SPLIT 16                 // chunk-blocks per row
#define NBLK  (BB * SPLIT)       // 2048 blocks = 8/CU exactly
#define F4_PER_CHUNK 2048        // 8192 elems / 4
#define F4_PER_STRIPE 8          // float4s per thread

typedef float v4f __attribute__((ext_vector_type(4)));

// sorted-insert into descending triple (a>=b>=c) in 3 depth-1 ops:
//   a' = max(a,v); b' = med3(a,b,v); c' = med3(b,c,v)
__device__ __forceinline__ void ins3(float v, float& a, float& b, float& c) {
    const float na = fmaxf(a, v);
    const float nb = __builtin_amdgcn_fmed3f(a, b, v);
    const float nc = __builtin_amdgcn_fmed3f(b, c, v);
    a = na; b = nb; c = nc;
}

__device__ __forceinline__ float bce(float x, float t) {
    return fmaxf(x, 0.0f) - x * t + log1pf(expf(-fabsf(x)));
}

// ---- Kernel 1: exact per-chunk top-3 (anchor excluded), NT stream ----
__global__ __launch_bounds__(256) void k_chunk_top3(
        const float* __restrict__ cp,
        const float* __restrict__ rp,
        const int*   __restrict__ box_idxs,
        const float* __restrict__ rt,
        float*       __restrict__ cand,     // [NBLK*3]
        float*       __restrict__ posval,   // [BB]
        float*       __restrict__ rowreg) { // [BB*CC]
    const int row   = blockIdx.x >> 4;
    const int chunk = blockIdx.x & 15;
    const int tid   = threadIdx.x;
    const int bidx  = box_idxs[row];

    // side jobs hidden under the stream (one chunk-0 block per row)
    if (chunk == 0) {
        if (tid < CC) {
            const float pv = rp[((size_t)row * CC + tid) * NBOXN + bidx];
            const float d  = fabsf(pv - rt[row * CC + tid]);
            rowreg[row * CC + tid] = (d < 1.0f) ? 0.5f * d * d : (d - 0.5f);
        } else if (tid == CC) {
            posval[row] = cp[(size_t)row * NBOXN + bidx];
        }
    }

    const v4f* src = reinterpret_cast<const v4f*>(cp + (size_t)row * NBOXN)
                     + chunk * F4_PER_CHUNK;
    const int gbase = (chunk * F4_PER_CHUNK) << 2;

    // per-thread exact top-3; nontemporal read-once stream; 3 VALU/elem
    float a = -FLT_MAX, b = -FLT_MAX, c = -FLT_MAX;
    #pragma unroll
    for (int k = 0; k < F4_PER_STRIPE; ++k) {
        const int j = tid + (k << 8);
        v4f v = __builtin_nontemporal_load(&src[j]);
        const int g = gbase + (j << 2);
        if ((unsigned)(bidx - g) < 4u) {     // rare, exec-mask-skipped
            if      (bidx == g)     v.x = -FLT_MAX;
            else if (bidx == g + 1) v.y = -FLT_MAX;
            else if (bidx == g + 2) v.z = -FLT_MAX;
            else                    v.w = -FLT_MAX;
        }
        ins3(v.x, a, b, c); ins3(v.y, a, b, c);
        ins3(v.z, a, b, c); ins3(v.w, a, b, c);
    }

    // wave64 shuffle tree; lane 0's cone covers all 64 lanes exactly once
    for (int off = 32; off >= 1; off >>= 1) {
        const float a2 = __shfl_down(a, off);
        const float b2 = __shfl_down(b, off);
        const float c2 = __shfl_down(c, off);
        ins3(a2, a, b, c); ins3(b2, a, b, c); ins3(c2, a, b, c);
    }

    __shared__ float sv[4][3];
    const int lane = tid & 63, wave = tid >> 6;
    if (lane == 0) { sv[wave][0] = a; sv[wave][1] = b; sv[wave][2] = c; }
    __syncthreads();
    if (tid == 0) {
        for (int w = 1; w < 4; ++w) {
            ins3(sv[w][0], a, b, c);
            ins3(sv[w][1], a, b, c);
            ins3(sv[w][2], a, b, c);
        }
        float* dst = cand + (size_t)blockIdx.x * 3;
        dst[0] = a; dst[1] = b; dst[2] = c;
    }
}

// ---- Kernel 2: merge 48 exact candidates/row + loss + scalar reduce ----
__global__ __launch_bounds__(128) void k_final(
        const float* __restrict__ cand,
        const float* __restrict__ posval,
        const float* __restrict__ rowreg,
        float*       __restrict__ out) {
    const int r = threadIdx.x;   // one row per thread

    // batched loads: 12 x dwordx4 (cand row) + 1 x dwordx4 (rowreg) + posval
    const v4f* pc = reinterpret_cast<const v4f*>(cand + (size_t)r * SPLIT * 3);
    v4f cv[12];
    #pragma unroll
    for (int q = 0; q < 12; ++q) cv[q] = pc[q];
    const v4f rg = reinterpret_cast<const v4f*>(rowreg)[r];
    const float pos = posval[r];

    float a = -FLT_MAX, b = -FLT_MAX, c = -FLT_MAX;
    #pragma unroll
    for (int q = 0; q < 12; ++q) {
        ins3(cv[q].x, a, b, c); ins3(cv[q].y, a, b, c);
        ins3(cv[q].z, a, b, c); ins3(cv[q].w, a, b, c);
    }

    float loss = bce(pos, 1.0f) + bce(a, 0.0f) + bce(b, 0.0f) + bce(c, 0.0f);
    loss += rg.x + rg.y + rg.z + rg.w;

    for (int off = 32; off >= 1; off >>= 1) loss += __shfl_down(loss, off);
    __shared__ float sm[2];
    if ((r & 63) == 0) sm[r >> 6] = loss;
    __syncthreads();
    if (r == 0) out[0] = (sm[0] + sm[1]) * (1.0f / (BB * CC));
}

extern "C" void kernel_launch(void* const* d_in, const int* in_sizes, int n_in,
                              void* d_out, int out_size, void* d_ws, size_t ws_size,
                              hipStream_t stream) {
    const float* class_preds = (const float*)d_in[0];
    const float* reg_preds   = (const float*)d_in[1];
    const int*   box_idxs    = (const int*)d_in[2];
    const float* reg_targs   = (const float*)d_in[3];
    float* out = (float*)d_out;

    float* cand   = (float*)d_ws;                   // NBLK*3 floats
    float* posval = cand + (size_t)NBLK * 3;        // BB floats
    float* rowreg = posval + BB;                    // BB*CC floats

    k_chunk_top3<<<NBLK, 256, 0, stream>>>(class_preds, reg_preds,
                                           box_idxs, reg_targs,
                                           cand, posval, rowreg);
    k_final<<<1, 128, 0, stream>>>(cand, posval, rowreg, out);
}